// Round 9
// baseline (276.639 us; speedup 1.0000x reference)
//
#include <hip/hip_runtime.h>

typedef unsigned short u16;
typedef unsigned int u32;
typedef __bf16 bf16x8 __attribute__((ext_vector_type(8)));
typedef float f32x4 __attribute__((ext_vector_type(4)));
typedef float f32x16 __attribute__((ext_vector_type(16)));
typedef int i32x4 __attribute__((ext_vector_type(4)));

#define AS1(p) ((const __attribute__((address_space(1))) void*)(p))
#define AS3(p) ((__attribute__((address_space(3))) void*)(p))

#if __has_builtin(__builtin_amdgcn_exp2f)
#define EXP2(x) __builtin_amdgcn_exp2f(x)
#else
#define EXP2(x) __builtin_exp2f(x)
#endif

__device__ __forceinline__ u16 f2bf(float f) {
    u32 u = __float_as_uint(f);
    u += 0x7fffu + ((u >> 16) & 1u);   // round-to-nearest-even
    return (u16)(u >> 16);
}

// packed f32x2 -> bf16x2 (RNE), low word = first operand
__device__ __forceinline__ int cvt_pk_bf16(float lo, float hi) {
    int r;
    asm("v_cvt_pk_bf16_f32 %0, %1, %2" : "=v"(r) : "v"(lo), "v"(hi));
    return r;
}

// Q/K/V/O buffers are each 24*4096*64 = 6291456 elements
#define NXQ 6291456
// Q scale: 1/sqrt(64) * log2(e), folded into Q projection so flash uses exp2
#define QSCALE 0.1803368801111249f

// ---------------- prep: x cast + 4x W transpose (bf16) + bias fuse ----------------
__global__ __launch_bounds__(256) void prep_kernel(
    const float* __restrict__ x,
    const float* __restrict__ wq, const float* __restrict__ wk,
    const float* __restrict__ wv, const float* __restrict__ wo,
    const float* __restrict__ bq, const float* __restrict__ bk,
    const float* __restrict__ bv,
    u16* __restrict__ xbf, u16* __restrict__ WT, float* __restrict__ bqkv)
{
    const int t = threadIdx.x;
    const int bid = blockIdx.x;
    if (bid < 6144) {                     // x: 8192*768 fp32 -> bf16
        int i = bid * 256 + t;
        float4 v = ((const float4*)x)[i];
        uint2 o;
        o.x = (u32)f2bf(v.x) | ((u32)f2bf(v.y) << 16);
        o.y = (u32)f2bf(v.z) | ((u32)f2bf(v.w) << 16);
        ((uint2*)xbf)[i] = o;
        return;
    }
    int tb = bid - 6144;                  // 0..575
    int mat = tb / 144;
    int tt = tb - mat * 144;
    int tr = tt / 12, tc = tt - tr * 12;
    const float* W = (mat == 0) ? wq : (mat == 1) ? wk : (mat == 2) ? wv : wo;
    __shared__ u16 sT[64 * 72];
    #pragma unroll
    for (int rr = 0; rr < 4; ++rr) {
        int r = (t >> 4) + rr * 16;
        int cb = (t & 15) * 4;
        float4 v = *(const float4*)&W[(size_t)(tr * 64 + r) * 768 + tc * 64 + cb];
        sT[(cb + 0) * 72 + r] = f2bf(v.x);
        sT[(cb + 1) * 72 + r] = f2bf(v.y);
        sT[(cb + 2) * 72 + r] = f2bf(v.z);
        sT[(cb + 3) * 72 + r] = f2bf(v.w);
    }
    __syncthreads();
    #pragma unroll
    for (int i = 0; i < 2; ++i) {
        int nr = t >> 2;
        int cc = (t & 3) * 16 + i * 8;
        *(uint4*)&WT[(size_t)(mat * 768 + tc * 64 + nr) * 768 + tr * 64 + cc] =
            *(uint4*)&sT[nr * 72 + cc];
    }
    if (tb < 9) {
        int i = tb * 256 + t;
        if (i < 2304)
            bqkv[i] = (i < 768) ? bq[i] : (i < 1536) ? bk[i - 768] : bv[i - 1536];
    }
}

// ---------------- GEMM: BK=64 single-buffer, global_load_lds + XOR swizzle --------
// [R1-verified main loop; R7 LDS-transpose epilogue (neutral, kept); R8 XCD
//  swizzle (neutral, kept). m112 tile study: 128^2 optimal for this 2-barrier
//  structure; ~390 TF here matches m102's short-K shape expectation -> at the
//  structural ceiling for this template.]
template<int MODE>
__global__ __launch_bounds__(256, 4) void gemm_kernel(
    const u16* __restrict__ A, const u16* __restrict__ WT,
    const float* __restrict__ bias, void* __restrict__ out)
{
    __shared__ __attribute__((aligned(16))) u16 smem[128 * 64 * 2];
    u16* sA = smem;
    u16* sB = smem + 128 * 64;

    // XCD swizzle: lin -> (lin%8)*(nwg/8) + lin/8, then back to 2D (x fastest)
    const int nx = gridDim.x;
    const int lin = blockIdx.y * nx + blockIdx.x;
    const int cpx = (nx * gridDim.y) >> 3;
    const int swz = (lin & 7) * cpx + (lin >> 3);
    const int bx = swz % nx, by = swz / nx;

    const int m0 = bx * 128;
    const int n0g = by * 128;
    const int tid = threadIdx.x, lane = tid & 63, wave = tid >> 6;
    const int quad = lane >> 4, l16 = lane & 15;
    const int wm = (wave & 1) * 64, wn = (wave >> 1) * 64;

    f32x4 acc[4][4];
    #pragma unroll
    for (int i = 0; i < 4; ++i)
        #pragma unroll
        for (int j = 0; j < 4; ++j)
            #pragma unroll
            for (int r = 0; r < 4; ++r)
                acc[i][j][r] = 0.f;

    const int srow = (lane >> 3);

    for (int k0 = 0; k0 < 768; k0 += 64) {
        __syncthreads();
        #pragma unroll
        for (int i = 0; i < 4; ++i) {
            int c = wave * 4 + i;
            int row = c * 8 + srow;
            __builtin_amdgcn_global_load_lds(
                AS1(&A[(size_t)(m0 + row) * 768 + k0 + (((lane & 7) ^ (row & 7)) * 8)]),
                AS3(&sA[c * 512]), 16, 0, 0);
            __builtin_amdgcn_global_load_lds(
                AS1(&WT[(size_t)(n0g + row) * 768 + k0 + (((lane & 7) ^ (row & 7)) * 8)]),
                AS3(&sB[c * 512]), 16, 0, 0);
        }
        __syncthreads();
        #pragma unroll
        for (int s = 0; s < 2; ++s) {
            bf16x8 af[4], bfr[4];
            #pragma unroll
            for (int i = 0; i < 4; ++i) {
                int row = wm + i * 16 + l16;
                af[i] = *(const bf16x8*)&sA[row * 64 + (((s * 4 + quad) ^ (row & 7)) * 8)];
            }
            #pragma unroll
            for (int j = 0; j < 4; ++j) {
                int row = wn + j * 16 + l16;
                bfr[j] = *(const bf16x8*)&sB[row * 64 + (((s * 4 + quad) ^ (row & 7)) * 8)];
            }
            #pragma unroll
            for (int i = 0; i < 4; ++i)
                #pragma unroll
                for (int j = 0; j < 4; ++j)
                    acc[i][j] = __builtin_amdgcn_mfma_f32_16x16x32_bf16(af[i], bfr[j], acc[i][j], 0, 0, 0);
        }
    }

    if (MODE == 0) {
        __syncthreads();                  // all LDS reads done; reuse smem as tile
        const int mat = by / 6;
        const int nm0 = n0g - mat * 768;
        const float scale = (mat == 0) ? QSCALE : 1.0f;
        u16* dst = (u16*)out + (size_t)mat * NXQ;
        u16* tile = smem;                 // [128][128] u16 = 32 KB
        const int b = m0 >> 12;
        const int h0 = nm0 >> 6;
        const int sbase = m0 & 4095;
        if (mat < 2) {
            // tile[s][col ^ (((s>>2)&3)<<4)] : swizzle bits 4-5, above 8-col runs
            #pragma unroll
            for (int i = 0; i < 4; ++i) {
                #pragma unroll
                for (int j = 0; j < 4; ++j) {
                    int col = wn + j * 16 + l16;
                    float bv = bias[n0g + col];
                    #pragma unroll
                    for (int r = 0; r < 4; ++r) {
                        int s = wm + i * 16 + quad * 4 + r;
                        tile[s * 128 + (col ^ ((((u32)s >> 2) & 3) << 4))] =
                            f2bf((acc[i][j][r] + bv) * scale);
                    }
                }
            }
            __syncthreads();
            #pragma unroll
            for (int it = 0; it < 8; ++it) {
                int u = it * 256 + tid;           // 0..2047 (16B units)
                int s = u >> 4;                   // 0..127
                int cc = (u & 15) * 8;            // logical col chunk
                int ccs = cc ^ ((((u32)s >> 2) & 3) << 4);
                uint4 v = *(const uint4*)&tile[s * 128 + ccs];
                int hh = cc >> 6, d = cc & 63;
                *(uint4*)&dst[(((size_t)(b * 12 + h0 + hh) * 4096) + sbase + s) * 64 + d] = v;
            }
        } else {
            // tile[col][s ^ ((col&7)<<3)] : swizzle bits 3-5, above 4/8-s runs
            #pragma unroll
            for (int i = 0; i < 4; ++i) {
                #pragma unroll
                for (int j = 0; j < 4; ++j) {
                    int col = wn + j * 16 + l16;
                    float bv = bias[n0g + col];
                    int s0 = wm + i * 16 + quad * 4;
                    ushort4 w;
                    w.x = f2bf(acc[i][j][0] + bv);
                    w.y = f2bf(acc[i][j][1] + bv);
                    w.z = f2bf(acc[i][j][2] + bv);
                    w.w = f2bf(acc[i][j][3] + bv);
                    *(ushort4*)&tile[col * 128 + (s0 ^ ((col & 7) << 3))] = w;
                }
            }
            __syncthreads();
            #pragma unroll
            for (int it = 0; it < 8; ++it) {
                int u = it * 256 + tid;           // 0..2047 (16B units)
                int col = u >> 4;                 // 0..127
                int sc = (u & 15) * 8;            // logical s chunk
                int scs = sc ^ ((col & 7) << 3);
                uint4 v = *(const uint4*)&tile[col * 128 + scs];
                int hh = col >> 6, d = col & 63;
                *(uint4*)&dst[(((size_t)(b * 12 + h0 + hh) * 64 + d) * 4096) + sbase + sc] = v;
            }
        }
    } else {
        #pragma unroll
        for (int i = 0; i < 4; ++i) {
            #pragma unroll
            for (int j = 0; j < 4; ++j) {
                int col = n0g + wn + j * 16 + l16;
                float bv = bias[col];
                #pragma unroll
                for (int r = 0; r < 4; ++r) {
                    int row = m0 + wm + i * 16 + quad * 4 + r;
                    ((float*)out)[(size_t)row * 768 + col] = acc[i][j][r] + bv;
                }
            }
        }
    }
}

// ---------------- flash attention: 32x32x16 MFMA, in-register P (no LDS round-trip)
// [R1/R4/R6/R7-verified body: 4 waves x 32q, 256 thr, 122.1-125.3 us across 4
//  benches. R8 V-hoist reverted (VGPR 80->84, +4us).]
// R9: bijective XCD block swizzle. Grid = 768 blocks at 3 blocks/CU -> whole
// grid co-resident. Default round-robin puts every 8th linear block on one XCD
// -> per-XCD K/V working set = all 24 bh = 24 MB >> 4 MB L2 -> ~770 MB of K/V
// re-reads served by L3 (FETCH 104 MB >> 63 MB working set = L3 thrash).
// Contiguous 96-block chunk per XCD = exactly 3 bh = 3 MB K/V < 4 MB L2.
// Pure index permutation: outputs bit-identical.
__global__ __launch_bounds__(256, 3) void flash_kernel(
    const u16* __restrict__ Q, const u16* __restrict__ K,
    const u16* __restrict__ Vt, u16* __restrict__ O)
{
    const int nx = gridDim.x;                       // 32
    const int lin = blockIdx.y * nx + blockIdx.x;   // 0..767
    const int cpx = (nx * gridDim.y) >> 3;          // 96
    const int swz = (lin & 7) * cpx + (lin >> 3);
    const int bh = swz >> 5;                        // swz / 32
    const int q0 = (swz & 31) * 128;

    const u16* Qp = Q + (size_t)bh * 4096 * 64;
    const u16* Kp = K + (size_t)bh * 4096 * 64;
    const u16* Vp = Vt + (size_t)bh * 64 * 4096;
    const int tid = threadIdx.x, lane = tid & 63, wave = tid >> 6;
    const int l32 = lane & 31, hf = lane >> 5;

    __shared__ u16 sK[2][64 * 64];    // [key][d], XOR-swizzled 16B chunks
    __shared__ u16 sVT[2][64 * 64];   // [d][key], XOR-swizzled 16B chunks

    const int qrow = q0 + wave * 32;
    // Q fragments (B-operand): qf[k16] = Q[qrow+l32][k16*16 + hf*8 .. +7]
    bf16x8 qf[4];
    #pragma unroll
    for (int k16 = 0; k16 < 4; ++k16)
        qf[k16] = *(const bf16x8*)&Qp[(size_t)(qrow + l32) * 64 + k16 * 16 + hf * 8];

    f32x16 oacc[2];
    #pragma unroll
    for (int dt = 0; dt < 2; ++dt)
        #pragma unroll
        for (int r = 0; r < 16; ++r)
            oacc[dt][r] = 0.f;
    float lpart = 0.f;

    const int srow = lane >> 3;
    auto stage = [&](int t, int buf) {
        #pragma unroll
        for (int i = 0; i < 2; ++i) {
            int c = wave * 2 + i;
            int row = c * 8 + srow;
            int kc = ((lane & 7) ^ ((row >> 2) & 7)) * 8;
            __builtin_amdgcn_global_load_lds(
                AS1(&Kp[(size_t)(t * 64 + row) * 64 + kc]),
                AS3(&sK[buf][c * 512]), 16, 0, 0);
            __builtin_amdgcn_global_load_lds(
                AS1(&Vp[(size_t)row * 4096 + t * 64 + kc]),
                AS3(&sVT[buf][c * 512]), 16, 0, 0);
        }
    };

    auto body = [&](int cur) {
        // S^T = K @ Q^T : two 32x32 tiles along the 64-key dim
        f32x16 sacc[2];
        #pragma unroll
        for (int kt = 0; kt < 2; ++kt)
            #pragma unroll
            for (int r = 0; r < 16; ++r)
                sacc[kt][r] = 0.f;
        __builtin_amdgcn_s_setprio(1);
        #pragma unroll
        for (int kt = 0; kt < 2; ++kt) {
            #pragma unroll
            for (int k16 = 0; k16 < 4; ++k16) {
                int row = kt * 32 + l32;
                bf16x8 ak = *(const bf16x8*)&sK[cur][row * 64 + (((k16 * 2 + hf) ^ ((row >> 2) & 7)) * 8)];
                sacc[kt] = __builtin_amdgcn_mfma_f32_32x32x16_bf16(ak, qf[k16], sacc[kt], 0, 0, 0);
            }
        }
        __builtin_amdgcn_s_setprio(0);

        // p = exp2(score); pack to bf16 pairs; accumulate l in f32
        int W[2][4][2];
        #pragma unroll
        for (int kt = 0; kt < 2; ++kt) {
            float p[16];
            #pragma unroll
            for (int r = 0; r < 16; ++r) p[r] = EXP2(sacc[kt][r]);
            lpart += (((p[0] + p[1]) + (p[2] + p[3])) + ((p[4] + p[5]) + (p[6] + p[7])))
                   + (((p[8] + p[9]) + (p[10] + p[11])) + ((p[12] + p[13]) + (p[14] + p[15])));
            #pragma unroll
            for (int g = 0; g < 4; ++g) {
                W[kt][g][0] = cvt_pk_bf16(p[g * 4 + 0], p[g * 4 + 1]);
                W[kt][g][1] = cvt_pk_bf16(p[g * 4 + 2], p[g * 4 + 3]);
            }
        }

        // Build PV B-frags in-register: frag[ks] keys = ks*16 + hf*8 + 0..7.
        // permlane32_swap(a,b): a' = [a.lo, b.lo], b' = [a.hi, b.hi].
        bf16x8 pf[4];
        #pragma unroll
        for (int ks = 0; ks < 4; ++ks) {
            int kt = ks >> 1, gA = (ks & 1) * 2;
            int a0 = W[kt][gA][0], b0 = W[kt][gA + 1][0];
            int a1 = W[kt][gA][1], b1 = W[kt][gA + 1][1];
            asm("v_permlane32_swap_b32 %0, %1" : "+v"(a0), "+v"(b0));
            asm("v_permlane32_swap_b32 %0, %1" : "+v"(a1), "+v"(b1));
            i32x4 t4;
            t4[0] = a0; t4[1] = a1; t4[2] = b0; t4[3] = b1;
            pf[ks] = __builtin_bit_cast(bf16x8, t4);
        }

        // O^T += V^T @ P^T : two 32x32 tiles along the 64-d dim
        __builtin_amdgcn_s_setprio(1);
        #pragma unroll
        for (int dt = 0; dt < 2; ++dt) {
            #pragma unroll
            for (int ks = 0; ks < 4; ++ks) {
                int row = dt * 32 + l32;
                bf16x8 av = *(const bf16x8*)&sVT[cur][row * 64 + (((ks * 2 + hf) ^ ((row >> 2) & 7)) * 8)];
                oacc[dt] = __builtin_amdgcn_mfma_f32_32x32x16_bf16(av, pf[ks], oacc[dt], 0, 0, 0);
            }
        }
        __builtin_amdgcn_s_setprio(0);
    };

    stage(0, 0);
    for (int t = 0; t < 64; t += 2) {
        __syncthreads();
        stage(t + 1, 1);
        body(0);
        __syncthreads();
        if (t + 2 < 64) stage(t + 2, 0);
        body(1);
    }

    // epilogue: l = own-half partial + other-half partial (per q=l32)
    float lfull = lpart + __shfl_xor(lpart, 32, 64);
    float inv = 1.0f / lfull;
    const int b = bh / 12, hh = bh - b * 12;
    const int token = qrow + l32;
    u16* Obase = O + ((size_t)(b * 4096 + token)) * 768 + hh * 64;
    #pragma unroll
    for (int dt = 0; dt < 2; ++dt) {
        #pragma unroll
        for (int g = 0; g < 4; ++g) {
            ushort4 w;
            w.x = f2bf(oacc[dt][g * 4 + 0] * inv);
            w.y = f2bf(oacc[dt][g * 4 + 1] * inv);
            w.z = f2bf(oacc[dt][g * 4 + 2] * inv);
            w.w = f2bf(oacc[dt][g * 4 + 3] * inv);
            *(ushort4*)&Obase[dt * 32 + g * 8 + hf * 4] = w;
        }
    }
}

extern "C" void kernel_launch(void* const* d_in, const int* in_sizes, int n_in,
                              void* d_out, int out_size, void* d_ws, size_t ws_size,
                              hipStream_t stream)
{
    (void)in_sizes; (void)n_in; (void)out_size; (void)ws_size;
    const float* x  = (const float*)d_in[0];
    const float* wq = (const float*)d_in[1];
    const float* bq = (const float*)d_in[2];
    const float* wk = (const float*)d_in[3];
    const float* bk = (const float*)d_in[4];
    const float* wv = (const float*)d_in[5];
    const float* bv = (const float*)d_in[6];
    const float* wo = (const float*)d_in[7];
    const float* bo = (const float*)d_in[8];
    float* out = (float*)d_out;

    u16* ws = (u16*)d_ws;
    u16* xbf = ws;                          // 8192*768
    u16* WT  = xbf + (size_t)8192 * 768;    // 3072*768 (WqT|WkT|WvT|WoT)
    u16* Qb  = WT + (size_t)3072 * 768;     // NXQ each
    u16* Kb  = Qb + NXQ;
    u16* Vtb = Kb + NXQ;
    u16* Ob  = Vtb + NXQ;
    float* bqkv = (float*)(Ob + NXQ);       // 2304 fp32

    prep_kernel<<<6720, 256, 0, stream>>>(x, wq, wk, wv, wo, bq, bk, bv, xbf, WT, bqkv);
    gemm_kernel<0><<<dim3(64, 18), 256, 0, stream>>>(xbf, WT, bqkv, Qb);
    flash_kernel<<<dim3(32, 24), 256, 0, stream>>>(Qb, Kb, Vtb, Ob);
    gemm_kernel<1><<<dim3(64, 6), 256, 0, stream>>>(Ob, WT + (size_t)2304 * 768, bo, out);
}

// Round 10
// 265.217 us; speedup vs baseline: 1.0431x; 1.0431x over previous
//
#include <hip/hip_runtime.h>

typedef unsigned short u16;
typedef unsigned int u32;
typedef __bf16 bf16x8 __attribute__((ext_vector_type(8)));
typedef float f32x4 __attribute__((ext_vector_type(4)));
typedef float f32x16 __attribute__((ext_vector_type(16)));
typedef int i32x4 __attribute__((ext_vector_type(4)));

#define AS1(p) ((const __attribute__((address_space(1))) void*)(p))
#define AS3(p) ((__attribute__((address_space(3))) void*)(p))

#if __has_builtin(__builtin_amdgcn_exp2f)
#define EXP2(x) __builtin_amdgcn_exp2f(x)
#else
#define EXP2(x) __builtin_exp2f(x)
#endif

__device__ __forceinline__ u16 f2bf(float f) {
    u32 u = __float_as_uint(f);
    u += 0x7fffu + ((u >> 16) & 1u);   // round-to-nearest-even
    return (u16)(u >> 16);
}

// packed f32x2 -> bf16x2 (RNE), low word = first operand
__device__ __forceinline__ int cvt_pk_bf16(float lo, float hi) {
    int r;
    asm("v_cvt_pk_bf16_f32 %0, %1, %2" : "=v"(r) : "v"(lo), "v"(hi));
    return r;
}

// Q/K/V/O buffers are each 24*4096*64 = 6291456 elements
#define NXQ 6291456
// Q scale: 1/sqrt(64) * log2(e), folded into Q projection so flash uses exp2
#define QSCALE 0.1803368801111249f

// ---------------- prep: x cast (grid-stride) + 4x W transpose + bias fuse ---------
// R10: x-cast was 6144 blocks x ONE float4/thread (launch/latency-bound shape);
// now 1536 blocks x 4 float4/thread (G11 grid-stride, 64B/thread).
__global__ __launch_bounds__(256) void prep_kernel(
    const float* __restrict__ x,
    const float* __restrict__ wq, const float* __restrict__ wk,
    const float* __restrict__ wv, const float* __restrict__ wo,
    const float* __restrict__ bq, const float* __restrict__ bk,
    const float* __restrict__ bv,
    u16* __restrict__ xbf, u16* __restrict__ WT, float* __restrict__ bqkv)
{
    const int t = threadIdx.x;
    const int bid = blockIdx.x;
    if (bid < 1536) {                     // x: 8192*768 fp32 -> bf16, 4 f4/thread
        #pragma unroll
        for (int k = 0; k < 4; ++k) {
            int i = bid * 256 + t + k * 393216;
            float4 v = ((const float4*)x)[i];
            uint2 o;
            o.x = (u32)f2bf(v.x) | ((u32)f2bf(v.y) << 16);
            o.y = (u32)f2bf(v.z) | ((u32)f2bf(v.w) << 16);
            ((uint2*)xbf)[i] = o;
        }
        return;
    }
    int tb = bid - 1536;                  // 0..575
    int mat = tb / 144;
    int tt = tb - mat * 144;
    int tr = tt / 12, tc = tt - tr * 12;
    const float* W = (mat == 0) ? wq : (mat == 1) ? wk : (mat == 2) ? wv : wo;
    __shared__ u16 sT[64 * 72];
    #pragma unroll
    for (int rr = 0; rr < 4; ++rr) {
        int r = (t >> 4) + rr * 16;
        int cb = (t & 15) * 4;
        float4 v = *(const float4*)&W[(size_t)(tr * 64 + r) * 768 + tc * 64 + cb];
        sT[(cb + 0) * 72 + r] = f2bf(v.x);
        sT[(cb + 1) * 72 + r] = f2bf(v.y);
        sT[(cb + 2) * 72 + r] = f2bf(v.z);
        sT[(cb + 3) * 72 + r] = f2bf(v.w);
    }
    __syncthreads();
    #pragma unroll
    for (int i = 0; i < 2; ++i) {
        int nr = t >> 2;
        int cc = (t & 3) * 16 + i * 8;
        *(uint4*)&WT[(size_t)(mat * 768 + tc * 64 + nr) * 768 + tr * 64 + cc] =
            *(uint4*)&sT[nr * 72 + cc];
    }
    if (tb < 9) {
        int i = tb * 256 + t;
        if (i < 2304)
            bqkv[i] = (i < 768) ? bq[i] : (i < 1536) ? bk[i - 768] : bv[i - 1536];
    }
}

// ---------------- GEMM: BK=64 single-buffer, global_load_lds + XOR swizzle --------
// [R1-exact: best-measured non-flash config (141.8 us). R7 epilogue and R8 XCD
//  swizzle were within +/-5 us noise -> dropped for simplicity. R4 BN=64 for
//  MODE 1 regressed ~9 us (staging-bound) -> 128x128 both modes.]
template<int MODE>
__global__ __launch_bounds__(256, 4) void gemm_kernel(
    const u16* __restrict__ A, const u16* __restrict__ WT,
    const float* __restrict__ bias, void* __restrict__ out)
{
    __shared__ u16 sA[128 * 64];
    __shared__ u16 sB[128 * 64];

    const int m0 = blockIdx.x * 128;
    const int n0g = blockIdx.y * 128;
    const int tid = threadIdx.x, lane = tid & 63, wave = tid >> 6;
    const int quad = lane >> 4, l16 = lane & 15;
    const int wm = (wave & 1) * 64, wn = (wave >> 1) * 64;

    f32x4 acc[4][4];
    #pragma unroll
    for (int i = 0; i < 4; ++i)
        #pragma unroll
        for (int j = 0; j < 4; ++j)
            #pragma unroll
            for (int r = 0; r < 4; ++r)
                acc[i][j][r] = 0.f;

    const int srow = (lane >> 3);

    for (int k0 = 0; k0 < 768; k0 += 64) {
        __syncthreads();
        #pragma unroll
        for (int i = 0; i < 4; ++i) {
            int c = wave * 4 + i;
            int row = c * 8 + srow;
            __builtin_amdgcn_global_load_lds(
                AS1(&A[(size_t)(m0 + row) * 768 + k0 + (((lane & 7) ^ (row & 7)) * 8)]),
                AS3(&sA[c * 512]), 16, 0, 0);
            __builtin_amdgcn_global_load_lds(
                AS1(&WT[(size_t)(n0g + row) * 768 + k0 + (((lane & 7) ^ (row & 7)) * 8)]),
                AS3(&sB[c * 512]), 16, 0, 0);
        }
        __syncthreads();
        #pragma unroll
        for (int s = 0; s < 2; ++s) {
            bf16x8 af[4], bfr[4];
            #pragma unroll
            for (int i = 0; i < 4; ++i) {
                int row = wm + i * 16 + l16;
                af[i] = *(const bf16x8*)&sA[row * 64 + (((s * 4 + quad) ^ (row & 7)) * 8)];
            }
            #pragma unroll
            for (int j = 0; j < 4; ++j) {
                int row = wn + j * 16 + l16;
                bfr[j] = *(const bf16x8*)&sB[row * 64 + (((s * 4 + quad) ^ (row & 7)) * 8)];
            }
            #pragma unroll
            for (int i = 0; i < 4; ++i)
                #pragma unroll
                for (int j = 0; j < 4; ++j)
                    acc[i][j] = __builtin_amdgcn_mfma_f32_16x16x32_bf16(af[i], bfr[j], acc[i][j], 0, 0, 0);
        }
    }

    if (MODE == 0) {
        const int mat = blockIdx.y / 6;
        const int nm0 = n0g - mat * 768;
        const float scale = (mat == 0) ? QSCALE : 1.0f;
        u16* dst = (u16*)out + (size_t)mat * NXQ;
        #pragma unroll
        for (int i = 0; i < 4; ++i) {
            #pragma unroll
            for (int j = 0; j < 4; ++j) {
                int colg = n0g + wn + j * 16 + l16;
                int col = nm0 + wn + j * 16 + l16;
                float bv = bias[colg];
                int h = col >> 6, d = col & 63;
                int row0 = m0 + wm + i * 16 + quad * 4;
                int b = row0 >> 12, s = row0 & 4095;
                if (mat < 2) {
                    #pragma unroll
                    for (int r = 0; r < 4; ++r)
                        dst[(((size_t)(b * 12 + h) * 4096) + s + r) * 64 + d] =
                            f2bf((acc[i][j][r] + bv) * scale);
                } else {
                    ushort4 w;
                    w.x = f2bf(acc[i][j][0] + bv);
                    w.y = f2bf(acc[i][j][1] + bv);
                    w.z = f2bf(acc[i][j][2] + bv);
                    w.w = f2bf(acc[i][j][3] + bv);
                    *(ushort4*)&dst[(((size_t)(b * 12 + h) * 64 + d) * 4096) + s] = w;
                }
            }
        }
    } else {
        #pragma unroll
        for (int i = 0; i < 4; ++i) {
            #pragma unroll
            for (int j = 0; j < 4; ++j) {
                int col = n0g + wn + j * 16 + l16;
                float bv = bias[col];
                #pragma unroll
                for (int r = 0; r < 4; ++r) {
                    int row = m0 + wm + i * 16 + quad * 4 + r;
                    ((float*)out)[(size_t)row * 768 + col] = acc[i][j][r] + bv;
                }
            }
        }
    }
}

// ---------------- flash attention: 32x32x16 MFMA, in-register P (no LDS round-trip)
// [R9-verified: 4 waves x 32q, 256 thr, 122.1-125.3 us across 5 benches. XCD
//  block swizzle keeps K/V L2-resident (FETCH 104->18.5 MB; time-neutral ->
//  staging latency fully hidden). LDS-read pipe (~61us busy + inherent b128
//  overhead, swizzle-invariant per R6) + VALU/TRANS (~55us) + MFMA (41us) bound
//  the 122-124us wall; reads/MFMA < 1.0 requires 64q/wave (R5: occupancy cliff)
//  or cross-wave key-split (R2: nondeterminism) -> structural floor for this
//  decomposition.]
__global__ __launch_bounds__(256, 3) void flash_kernel(
    const u16* __restrict__ Q, const u16* __restrict__ K,
    const u16* __restrict__ Vt, u16* __restrict__ O)
{
    const int nx = gridDim.x;                       // 32
    const int lin = blockIdx.y * nx + blockIdx.x;   // 0..767
    const int cpx = (nx * gridDim.y) >> 3;          // 96
    const int swz = (lin & 7) * cpx + (lin >> 3);
    const int bh = swz >> 5;                        // swz / 32
    const int q0 = (swz & 31) * 128;

    const u16* Qp = Q + (size_t)bh * 4096 * 64;
    const u16* Kp = K + (size_t)bh * 4096 * 64;
    const u16* Vp = Vt + (size_t)bh * 64 * 4096;
    const int tid = threadIdx.x, lane = tid & 63, wave = tid >> 6;
    const int l32 = lane & 31, hf = lane >> 5;

    __shared__ u16 sK[2][64 * 64];    // [key][d], XOR-swizzled 16B chunks
    __shared__ u16 sVT[2][64 * 64];   // [d][key], XOR-swizzled 16B chunks

    const int qrow = q0 + wave * 32;
    // Q fragments (B-operand): qf[k16] = Q[qrow+l32][k16*16 + hf*8 .. +7]
    bf16x8 qf[4];
    #pragma unroll
    for (int k16 = 0; k16 < 4; ++k16)
        qf[k16] = *(const bf16x8*)&Qp[(size_t)(qrow + l32) * 64 + k16 * 16 + hf * 8];

    f32x16 oacc[2];
    #pragma unroll
    for (int dt = 0; dt < 2; ++dt)
        #pragma unroll
        for (int r = 0; r < 16; ++r)
            oacc[dt][r] = 0.f;
    float lpart = 0.f;

    const int srow = lane >> 3;
    auto stage = [&](int t, int buf) {
        #pragma unroll
        for (int i = 0; i < 2; ++i) {
            int c = wave * 2 + i;
            int row = c * 8 + srow;
            int kc = ((lane & 7) ^ ((row >> 2) & 7)) * 8;
            __builtin_amdgcn_global_load_lds(
                AS1(&Kp[(size_t)(t * 64 + row) * 64 + kc]),
                AS3(&sK[buf][c * 512]), 16, 0, 0);
            __builtin_amdgcn_global_load_lds(
                AS1(&Vp[(size_t)row * 4096 + t * 64 + kc]),
                AS3(&sVT[buf][c * 512]), 16, 0, 0);
        }
    };

    auto body = [&](int cur) {
        // S^T = K @ Q^T : two 32x32 tiles along the 64-key dim
        f32x16 sacc[2];
        #pragma unroll
        for (int kt = 0; kt < 2; ++kt)
            #pragma unroll
            for (int r = 0; r < 16; ++r)
                sacc[kt][r] = 0.f;
        __builtin_amdgcn_s_setprio(1);
        #pragma unroll
        for (int kt = 0; kt < 2; ++kt) {
            #pragma unroll
            for (int k16 = 0; k16 < 4; ++k16) {
                int row = kt * 32 + l32;
                bf16x8 ak = *(const bf16x8*)&sK[cur][row * 64 + (((k16 * 2 + hf) ^ ((row >> 2) & 7)) * 8)];
                sacc[kt] = __builtin_amdgcn_mfma_f32_32x32x16_bf16(ak, qf[k16], sacc[kt], 0, 0, 0);
            }
        }
        __builtin_amdgcn_s_setprio(0);

        // p = exp2(score); pack to bf16 pairs; accumulate l in f32
        int W[2][4][2];
        #pragma unroll
        for (int kt = 0; kt < 2; ++kt) {
            float p[16];
            #pragma unroll
            for (int r = 0; r < 16; ++r) p[r] = EXP2(sacc[kt][r]);
            lpart += (((p[0] + p[1]) + (p[2] + p[3])) + ((p[4] + p[5]) + (p[6] + p[7])))
                   + (((p[8] + p[9]) + (p[10] + p[11])) + ((p[12] + p[13]) + (p[14] + p[15])));
            #pragma unroll
            for (int g = 0; g < 4; ++g) {
                W[kt][g][0] = cvt_pk_bf16(p[g * 4 + 0], p[g * 4 + 1]);
                W[kt][g][1] = cvt_pk_bf16(p[g * 4 + 2], p[g * 4 + 3]);
            }
        }

        // Build PV B-frags in-register: frag[ks] keys = ks*16 + hf*8 + 0..7.
        // permlane32_swap(a,b): a' = [a.lo, b.lo], b' = [a.hi, b.hi].
        bf16x8 pf[4];
        #pragma unroll
        for (int ks = 0; ks < 4; ++ks) {
            int kt = ks >> 1, gA = (ks & 1) * 2;
            int a0 = W[kt][gA][0], b0 = W[kt][gA + 1][0];
            int a1 = W[kt][gA][1], b1 = W[kt][gA + 1][1];
            asm("v_permlane32_swap_b32 %0, %1" : "+v"(a0), "+v"(b0));
            asm("v_permlane32_swap_b32 %0, %1" : "+v"(a1), "+v"(b1));
            i32x4 t4;
            t4[0] = a0; t4[1] = a1; t4[2] = b0; t4[3] = b1;
            pf[ks] = __builtin_bit_cast(bf16x8, t4);
        }

        // O^T += V^T @ P^T : two 32x32 tiles along the 64-d dim
        __builtin_amdgcn_s_setprio(1);
        #pragma unroll
        for (int dt = 0; dt < 2; ++dt) {
            #pragma unroll
            for (int ks = 0; ks < 4; ++ks) {
                int row = dt * 32 + l32;
                bf16x8 av = *(const bf16x8*)&sVT[cur][row * 64 + (((ks * 2 + hf) ^ ((row >> 2) & 7)) * 8)];
                oacc[dt] = __builtin_amdgcn_mfma_f32_32x32x16_bf16(av, pf[ks], oacc[dt], 0, 0, 0);
            }
        }
        __builtin_amdgcn_s_setprio(0);
    };

    stage(0, 0);
    for (int t = 0; t < 64; t += 2) {
        __syncthreads();
        stage(t + 1, 1);
        body(0);
        __syncthreads();
        if (t + 2 < 64) stage(t + 2, 0);
        body(1);
    }

    // epilogue: l = own-half partial + other-half partial (per q=l32)
    float lfull = lpart + __shfl_xor(lpart, 32, 64);
    float inv = 1.0f / lfull;
    const int b = bh / 12, hh = bh - b * 12;
    const int token = qrow + l32;
    u16* Obase = O + ((size_t)(b * 4096 + token)) * 768 + hh * 64;
    #pragma unroll
    for (int dt = 0; dt < 2; ++dt) {
        #pragma unroll
        for (int g = 0; g < 4; ++g) {
            ushort4 w;
            w.x = f2bf(oacc[dt][g * 4 + 0] * inv);
            w.y = f2bf(oacc[dt][g * 4 + 1] * inv);
            w.z = f2bf(oacc[dt][g * 4 + 2] * inv);
            w.w = f2bf(oacc[dt][g * 4 + 3] * inv);
            *(ushort4*)&Obase[dt * 32 + g * 8 + hf * 4] = w;
        }
    }
}

extern "C" void kernel_launch(void* const* d_in, const int* in_sizes, int n_in,
                              void* d_out, int out_size, void* d_ws, size_t ws_size,
                              hipStream_t stream)
{
    (void)in_sizes; (void)n_in; (void)out_size; (void)ws_size;
    const float* x  = (const float*)d_in[0];
    const float* wq = (const float*)d_in[1];
    const float* bq = (const float*)d_in[2];
    const float* wk = (const float*)d_in[3];
    const float* bk = (const float*)d_in[4];
    const float* wv = (const float*)d_in[5];
    const float* bv = (const float*)d_in[6];
    const float* wo = (const float*)d_in[7];
    const float* bo = (const float*)d_in[8];
    float* out = (float*)d_out;

    u16* ws = (u16*)d_ws;
    u16* xbf = ws;                          // 8192*768
    u16* WT  = xbf + (size_t)8192 * 768;    // 3072*768 (WqT|WkT|WvT|WoT)
    u16* Qb  = WT + (size_t)3072 * 768;     // NXQ each
    u16* Kb  = Qb + NXQ;
    u16* Vtb = Kb + NXQ;
    u16* Ob  = Vtb + NXQ;
    float* bqkv = (float*)(Ob + NXQ);       // 2304 fp32

    prep_kernel<<<2112, 256, 0, stream>>>(x, wq, wk, wv, wo, bq, bk, bv, xbf, WT, bqkv);
    gemm_kernel<0><<<dim3(64, 18), 256, 0, stream>>>(xbf, WT, bqkv, Qb);
    flash_kernel<<<dim3(32, 24), 256, 0, stream>>>(Qb, Kb, Vtb, Ob);
    gemm_kernel<1><<<dim3(64, 6), 256, 0, stream>>>(Ob, WT + (size_t)2304 * 768, bo, out);
}